// Round 4
// baseline (363.890 us; speedup 1.0000x reference)
//
#include <hip/hip_runtime.h>
#include <stdint.h>

// ---------- common helpers ----------
typedef __attribute__((ext_vector_type(8))) short bf16x8;   // 8 bf16 (4 VGPRs)
typedef __attribute__((ext_vector_type(4))) float f32x4;    // MFMA accumulator

#define AS1 __attribute__((address_space(1)))
#define AS3 __attribute__((address_space(3)))

// async global->LDS, 16B per lane; LDS dest = wave-uniform base + lane*16.
__device__ __forceinline__ void gl2lds16(const void* g, void* l) {
    __builtin_amdgcn_global_load_lds((const AS1 void*)g, (AS3 void*)l, 16, 0, 0);
}

__device__ __forceinline__ unsigned short f2bf(float f) {
    uint32_t u = __builtin_bit_cast(uint32_t, f);
    uint32_t r = (u + 0x7fffu + ((u >> 16) & 1u)) >> 16;    // RNE
    return (unsigned short)r;
}

// ---------- problem constants ----------
// B=4, S=4096, H=512
constexpr int S = 4096;
constexpr int H = 512;
constexpr size_t OFF_XB  = 0;                         // x  bf16   [4*4096*512]
constexpr size_t OFF_SB  = 16777216;                  // x+rp bf16 (contiguous after xb)
constexpr size_t OFF_WQB = 33554432;                  // Wq bf16 [512*512]
constexpr size_t OFF_WKB = 34078720;                  // Wk bf16 (contiguous after Wq)
constexpr size_t OFF_WVB = 34603008;
constexpr size_t OFF_BQK = 35127296;                  // fp32 [2][512]: row0=bq, row1=2*bk
constexpr size_t OFF_QB  = 35131392;                  // Q bf16 [4][4096][512]
constexpr size_t OFF_K2B = OFF_QB  + 16777216;        // K+Kr bf16 (contiguous after Q)
constexpr size_t OFF_VTB = OFF_K2B + 16777216;        // V^T bf16 [4][512][4096]
constexpr size_t OFF_PB  = OFF_VTB + 16777216;        // P = exp(scores) bf16 [4][4096][4096]
constexpr size_t OFF_L   = OFF_PB  + 134217728;       // row sums fp32 [4][4096]

// ---------- fused prep: casts, x+rp fusion, bias prep, lrow zero ----------
__global__ __launch_bounds__(256) void prep_all(const float* __restrict__ x,
                                                const float* __restrict__ rp,
                                                const float* __restrict__ wq,
                                                const float* __restrict__ wk,
                                                const float* __restrict__ wv,
                                                const float* __restrict__ bq,
                                                const float* __restrict__ bk,
                                                unsigned short* __restrict__ xb,
                                                unsigned short* __restrict__ sb,
                                                unsigned short* __restrict__ wqb,
                                                unsigned short* __restrict__ wkb,
                                                unsigned short* __restrict__ wvb,
                                                float* __restrict__ bqk,
                                                float* __restrict__ lrow) {
    if (blockIdx.x < 8192) {
        const int i = (blockIdx.x * 256 + threadIdx.x) * 4;
        float4 xv = *(const float4*)(x + i);
        float4 rv = *(const float4*)(rp + i);
        uint2 xo, so;
        xo.x = (uint32_t)f2bf(xv.x) | ((uint32_t)f2bf(xv.y) << 16);
        xo.y = (uint32_t)f2bf(xv.z) | ((uint32_t)f2bf(xv.w) << 16);
        so.x = (uint32_t)f2bf(xv.x + rv.x) | ((uint32_t)f2bf(xv.y + rv.y) << 16);
        so.y = (uint32_t)f2bf(xv.z + rv.z) | ((uint32_t)f2bf(xv.w + rv.w) << 16);
        *(uint2*)(xb + i) = xo;
        *(uint2*)(sb + i) = so;
    } else {
        const int t = (blockIdx.x - 8192) * 256 + threadIdx.x;   // 0..65535
        const int i = t * 4;
        float4 q = *(const float4*)(wq + i);
        float4 k = *(const float4*)(wk + i);
        float4 v = *(const float4*)(wv + i);
        uint2 o;
        o.x = (uint32_t)f2bf(q.x) | ((uint32_t)f2bf(q.y) << 16);
        o.y = (uint32_t)f2bf(q.z) | ((uint32_t)f2bf(q.w) << 16);
        *(uint2*)(wqb + i) = o;
        o.x = (uint32_t)f2bf(k.x) | ((uint32_t)f2bf(k.y) << 16);
        o.y = (uint32_t)f2bf(k.z) | ((uint32_t)f2bf(k.w) << 16);
        *(uint2*)(wkb + i) = o;
        o.x = (uint32_t)f2bf(v.x) | ((uint32_t)f2bf(v.y) << 16);
        o.y = (uint32_t)f2bf(v.z) | ((uint32_t)f2bf(v.w) << 16);
        *(uint2*)(wvb + i) = o;
        if (t < 128) {                                    // row0 = bq
            *(float4*)(bqk + t * 4) = *(const float4*)(bq + t * 4);
        } else if (t < 256) {                             // row1 = 2*bk
            const int u = t - 128;
            float4 b = *(const float4*)(bk + u * 4);
            *(float4*)(bqk + 512 + u * 4) = make_float4(2.f * b.x, 2.f * b.y, 2.f * b.z, 2.f * b.w);
        }
        if (t < 4096) {                                   // lrow[16384] = 0
            *(float4*)(lrow + t * 4) = make_float4(0.f, 0.f, 0.f, 0.f);
        }
    }
}

// ---------- generic bt-form bf16 MFMA GEMM (m97 structure, kept for small GEMMs + PV) ----------
template <int MODE, int SWZ, int NPANEL>
__global__ __launch_bounds__(256, 2)
void gemm_bt(const unsigned short* __restrict__ Abase,
             const unsigned short* __restrict__ Bbase,
             void* __restrict__ Cbase,
             int M, int N, int K,
             long long sAz, long long sBz, long long sCz,
             const float* __restrict__ bias_n, long long sBNz,
             const float* __restrict__ bias_m,
             float scale,
             float* __restrict__ rowdiv, long long sRz)
{
    int bx = blockIdx.x, by = blockIdx.y, bz = blockIdx.z;
    if (SWZ) {
        const int gx = gridDim.x, gy = gridDim.y;
        const int id  = bx + gx * (by + gridDim.y * bz);
        const int xcd = id & 7;
        const int k   = id >> 3;
        const int kg  = k / gx;
        bx = k - kg * gx;
        const int g = xcd + 8 * kg;
        const int gz = g / gy;
        by = g - gz * gy;
        bz = gz;
    }
    const int z = bz;
    const unsigned short* A  = Abase + (size_t)z * (size_t)sAz;
    const unsigned short* Bm = Bbase + (size_t)z * (size_t)sBz;
    const int bn = bx * 128;
    const int bm = by * 128;

    constexpr int STAGE_BYTES = NPANEL * 16384;
    constexpr int SMEM_BYTES = (MODE == 1) ? STAGE_BYTES
                             : (STAGE_BYTES > 34816 ? STAGE_BYTES : 34816);
    __shared__ __align__(16) char smem[SMEM_BYTES];
    unsigned short* As = (unsigned short*)smem;                       // [NPANEL][128][32]
    unsigned short* Bs = (unsigned short*)(smem + NPANEL * 8192);     // [NPANEL][128][32]

    const int tid  = threadIdx.x;
    const int wave = tid >> 6;
    const int lane = tid & 63;
    const int lm   = lane & 15;
    const int quad = lane >> 4;
    const int wm   = (wave >> 1) * 64;
    const int wn   = (wave & 1) * 64;

    const int r0 = tid >> 2;
    const int p0 = tid & 3;

    f32x4 acc[4][4] = {};

    for (int k0 = 0; k0 < K; k0 += 32 * NPANEL) {
        __syncthreads();
        #pragma unroll
        for (int pp = 0; pp < NPANEL; pp++) {
            const unsigned short* Ap = A  + (size_t)(bm + r0) * K + k0 + pp * 32 + p0 * 8;
            const unsigned short* Bp = Bm + (size_t)(bn + r0) * K + k0 + pp * 32 + p0 * 8;
            unsigned short* Asp = As + pp * 4096;
            unsigned short* Bsp = Bs + pp * 4096;
            gl2lds16(Ap,                    Asp + wave * 512);
            gl2lds16(Ap + (size_t)64 * K,   Asp + 2048 + wave * 512);
            gl2lds16(Bp,                    Bsp + wave * 512);
            gl2lds16(Bp + (size_t)64 * K,   Bsp + 2048 + wave * 512);
        }
        __syncthreads();

        #pragma unroll
        for (int pp = 0; pp < NPANEL; pp++) {
            bf16x8 af[4], bfr[4];
            #pragma unroll
            for (int t = 0; t < 4; t++)
                af[t]  = *(const bf16x8*)(As + pp * 4096 + (wm + t * 16 + lm) * 32 + quad * 8);
            #pragma unroll
            for (int t = 0; t < 4; t++)
                bfr[t] = *(const bf16x8*)(Bs + pp * 4096 + (wn + t * 16 + lm) * 32 + quad * 8);
            #pragma unroll
            for (int mt = 0; mt < 4; mt++)
                #pragma unroll
                for (int nt = 0; nt < 4; nt++)
                    acc[mt][nt] = __builtin_amdgcn_mfma_f32_16x16x32_bf16(af[mt], bfr[nt], acc[mt][nt], 0, 0, 0);
        }
    }

    if (MODE == 1) {
        float* C = (float*)Cbase + (size_t)z * (size_t)sCz;
        const float* rd = rowdiv + (size_t)z * (size_t)sRz;
        #pragma unroll
        for (int mt = 0; mt < 4; mt++) {
            #pragma unroll
            for (int i = 0; i < 4; i++) {
                const int row = bm + wm + mt * 16 + quad * 4 + i;
                const float inv = 1.0f / rd[row];
                const size_t rb = (size_t)row * (size_t)N;
                #pragma unroll
                for (int nt = 0; nt < 4; nt++) {
                    const int col = bn + wn + nt * 16 + lm;
                    C[rb + col] = acc[mt][nt][i] * inv;
                }
            }
        }
    } else {
        unsigned short* C = (unsigned short*)Cbase + (size_t)z * (size_t)sCz;
        const float* bn_ptr = (MODE == 0 && bias_n) ? bias_n + (size_t)z * (size_t)sBNz : nullptr;
        float* lr = (MODE == 2) ? rowdiv + (size_t)z * (size_t)sRz : nullptr;
        unsigned short* Ct = (unsigned short*)smem;   // 128 x 136 bf16 tile
        __syncthreads();
        #pragma unroll
        for (int mt = 0; mt < 4; mt++) {
            #pragma unroll
            for (int i = 0; i < 4; i++) {
                const int r = wm + mt * 16 + quad * 4 + i;
                if (MODE == 0) {
                    const float badd = bias_m ? bias_m[bm + r] : 0.0f;
                    #pragma unroll
                    for (int nt = 0; nt < 4; nt++) {
                        const int col = bn + wn + nt * 16 + lm;
                        float v = acc[mt][nt][i] * scale + badd;
                        if (bn_ptr) v += bn_ptr[col];
                        Ct[r * 136 + wn + nt * 16 + lm] = f2bf(v);
                    }
                } else {
                    float rsum = 0.f;
                    #pragma unroll
                    for (int nt = 0; nt < 4; nt++) {
                        float p = __expf(acc[mt][nt][i] * scale);
                        rsum += p;
                        Ct[r * 136 + wn + nt * 16 + lm] = f2bf(p);
                    }
                    rsum += __shfl_xor(rsum, 1);
                    rsum += __shfl_xor(rsum, 2);
                    rsum += __shfl_xor(rsum, 4);
                    rsum += __shfl_xor(rsum, 8);
                    if (lm == 0) atomicAdd(lr + bm + r, rsum);
                }
            }
        }
        __syncthreads();
        #pragma unroll
        for (int j = 0; j < 8; j++) {
            const int r   = (tid >> 4) + 16 * j;
            const int c16 = tid & 15;
            uint4 vv = *(const uint4*)(Ct + r * 136 + c16 * 8);
            *(uint4*)(C + (size_t)(bm + r) * (size_t)N + bn + c16 * 8) = vv;
        }
    }
}

// ---------- 2-phase 256x256 BK=64 score kernel: P = exp(Q@K2^T * scale), lrow += rowsums ----------
// 512 threads = 8 waves (2 row-groups x 4 col-groups). Catalog "minimum 2-phase"
// recipe: body T stages tile T+1 into the OTHER buffer (1-tile lead -- round 3's
// bug was a 2-tile lead into the buffer being read, a plain LDS race), computes
// tile T from its own buffer with counted lgkmcnt so ds_read overlaps MFMA, then
// vmcnt(0)+barrier. The vmcnt(0) drain is cheap: loads issue at body START and
// the ~2500-cycle body exceeds HBM latency (issue-early / drain-late, T14).
// Sync per K-loop: 8 barriers + 7 vmcnt(0)  (round 2: 64 barriers -> 21% MfmaUtil).
// T2 swizzle (verified round 2: SQ_LDS_BANK_CONFLICT = 0) and epilogue unchanged.
__global__ __launch_bounds__(512, 2)
void qk_exp_8ph(const unsigned short* __restrict__ Qb,
                const unsigned short* __restrict__ K2b,
                unsigned short* __restrict__ Pb,
                float* __restrict__ lrow)
{
    constexpr int N  = 4096;
    constexpr int Kd = 512;
    constexpr float scale = 0.044194173824159216f;
    __shared__ __align__(16) char smem8[131072];

    int bx = blockIdx.x, by = blockIdx.y, bz = blockIdx.z;
    {   // XCD swizzle (nwg = 1024 = 8*128, bijective)
        const int gx = gridDim.x, gy = gridDim.y;
        const int id  = bx + gx * (by + gy * bz);
        const int xcd = id & 7;
        const int k   = id >> 3;
        const int kg  = k / gx;
        bx = k - kg * gx;
        const int g = xcd + 8 * kg;
        const int gz = g / gy;
        by = g - gz * gy;
        bz = gz;
    }
    const int z  = bz;
    const int bm = by * 256;
    const int bn = bx * 256;
    const unsigned short* Az = Qb  + (size_t)z * (size_t)N * Kd;
    const unsigned short* Bz = K2b + (size_t)z * (size_t)N * Kd;

    unsigned short* A0 = (unsigned short*)smem8;       // [256][64] bf16, 32 KB each
    unsigned short* B0 = A0 + 256 * 64;
    unsigned short* A1 = B0 + 256 * 64;
    unsigned short* B1 = A1 + 256 * 64;

    const int tid  = threadIdx.x;
    const int wave = tid >> 6;
    const int lane = tid & 63;
    const int lm   = lane & 15;
    const int quad = lane >> 4;
    const int r2   = wave >> 2;      // 0..1 : 64-row group within 128-half
    const int c4   = wave & 3;       // 0..3 : 32-col group within 128-half

    // staging: lane covers LDS line (row = base + lane>>3, slot = lane&7);
    // global source slot pre-swizzled: slot' = (lane&7) ^ (row&7), row&7 == lane>>3.
    const int srcslot = (lane & 7) ^ ((lane >> 3) & 7);
    const unsigned short* aSt = Az + (size_t)(bm + wave * 16 + (lane >> 3)) * Kd + srcslot * 8;
    const unsigned short* bSt = Bz + (size_t)(bn + wave * 16 + (lane >> 3)) * Kd + srcslot * 8;
    unsigned short* aLd0 = A0 + wave * 16 * 64;
    unsigned short* bLd0 = B0 + wave * 16 * 64;
    unsigned short* aLd1 = A1 + wave * 16 * 64;
    unsigned short* bLd1 = B1 + wave * 16 * 64;

    // stage half h (128 rows) of K-tile t: 2 x gl2lds16 (8 rows x 64k = 1KB each)
#define STG(gbase, ld, t, h) { \
    gl2lds16((gbase) + (h) * 128 * Kd + (t) * 64,          (ld) + (h) * 128 * 64); \
    gl2lds16((gbase) + (h) * 128 * Kd + 8 * Kd + (t) * 64, (ld) + (h) * 128 * 64 + 8 * 64); }

    // stage FULL K-tile t into buffer (A and B): 8 gl2lds16 per wave
#define STG_TILE(ald, bld, t) { \
    STG(aSt, ald, t, 0); STG(aSt, ald, t, 1); \
    STG(bSt, bld, t, 0); STG(bSt, bld, t, 1); }

    f32x4 acc[2][2][4][2] = {};
    bf16x8 af[4][2], bf0[2][2], bf1[2][2];

#define LD_AF(Abuf, HM) { _Pragma("unroll") for (int m = 0; m < 4; ++m) { \
      const int row_ = (HM) * 128 + r2 * 64 + m * 16 + lm; \
      const char* rp_ = (const char*)(Abuf) + row_ * 128; \
      const int sw_ = (row_ & 7) << 4; \
      af[m][0] = *(const bf16x8*)(rp_ + ((quad * 16) ^ sw_)); \
      af[m][1] = *(const bf16x8*)(rp_ + ((64 + quad * 16) ^ sw_)); } }

#define LD_BF(dst, Bbuf, HN) { _Pragma("unroll") for (int n = 0; n < 2; ++n) { \
      const int row_ = (HN) * 128 + c4 * 32 + n * 16 + lm; \
      const char* rp_ = (const char*)(Bbuf) + row_ * 128; \
      const int sw_ = (row_ & 7) << 4; \
      dst[n][0] = *(const bf16x8*)(rp_ + ((quad * 16) ^ sw_)); \
      dst[n][1] = *(const bf16x8*)(rp_ + ((64 + quad * 16) ^ sw_)); } }

#define MM(HM, HN, BF) { _Pragma("unroll") for (int m = 0; m < 4; ++m) \
      _Pragma("unroll") for (int n = 0; n < 2; ++n) \
      _Pragma("unroll") for (int ks = 0; ks < 2; ++ks) \
        acc[HM][HN][m][n] = __builtin_amdgcn_mfma_f32_16x16x32_bf16(af[m][ks], BF[n][ks], acc[HM][HN][m][n], 0, 0, 0); }

    // ---- prologue: stage tile 0 into buf0; drain; barrier ----
    STG_TILE(aLd0, bLd0, 0);
    asm volatile("s_waitcnt vmcnt(0)" ::: "memory");
    __builtin_amdgcn_s_barrier();

    // ---- K-loop: 8 tiles; body T stages T+1 into the OTHER buffer (1-tile lead) ----
    // Safety: other buffer's last reads completed before the end-of-body-(T-1)
    // barrier, so staging into it at body-T start cannot race any read. The
    // vmcnt(0) at body end retires exactly the 8 loads issued at body start.
#define TILE_BODY(T, AB, BB, ALD_O, BLD_O) { \
    if ((T) + 1 < 8) { STG_TILE(ALD_O, BLD_O, (T) + 1); } \
    LD_AF(AB, 0); LD_BF(bf0, BB, 0); LD_BF(bf1, BB, 1); \
    asm volatile("s_waitcnt lgkmcnt(4)" ::: "memory"); \
    __builtin_amdgcn_sched_barrier(0); \
    __builtin_amdgcn_s_setprio(1); \
    MM(0, 0, bf0); \
    __builtin_amdgcn_s_setprio(0); \
    asm volatile("s_waitcnt lgkmcnt(0)" ::: "memory"); \
    __builtin_amdgcn_sched_barrier(0); \
    __builtin_amdgcn_s_setprio(1); \
    MM(0, 1, bf1); \
    __builtin_amdgcn_s_setprio(0); \
    LD_AF(AB, 1); \
    asm volatile("s_waitcnt lgkmcnt(0)" ::: "memory"); \
    __builtin_amdgcn_sched_barrier(0); \
    __builtin_amdgcn_s_setprio(1); \
    MM(1, 0, bf0); \
    MM(1, 1, bf1); \
    __builtin_amdgcn_s_setprio(0); \
    if ((T) + 1 < 8) { asm volatile("s_waitcnt vmcnt(0)" ::: "memory"); } \
    __builtin_amdgcn_s_barrier(); }

    #pragma unroll
    for (int tp = 0; tp < 4; ++tp) {
        TILE_BODY(2 * tp,     A0, B0, aLd1, bLd1);   // compute buf0, stage ->buf1
        TILE_BODY(2 * tp + 1, A1, B1, aLd0, bLd0);   // compute buf1, stage ->buf0
    }
    // trailing barrier of tile 7 doubles as the pre-epilogue read-drain barrier

    // ---- epilogue: exp + rowsum, swizzled LDS restage, coalesced store ----
    asm volatile("" ::: "memory");
    unsigned short* Ct = (unsigned short*)smem8;          // [256] rows x 512 B, same XOR swizzle
    float* lr = lrow + (size_t)z * 4096;
    unsigned short* Cz = Pb + (size_t)z * (size_t)N * N;

    #pragma unroll
    for (int hm = 0; hm < 2; ++hm)
    #pragma unroll
    for (int m = 0; m < 4; ++m)
    #pragma unroll
    for (int i2 = 0; i2 < 4; ++i2) {
        const int row = hm * 128 + r2 * 64 + m * 16 + quad * 4 + i2;  // C/D: row=quad*4+reg
        char* rowp = (char*)Ct + row * 512;
        const int sw = (row & 7) << 4;
        float rs = 0.f;
        #pragma unroll
        for (int hn = 0; hn < 2; ++hn)
        #pragma unroll
        for (int n = 0; n < 2; ++n) {
            const float p = __expf(acc[hm][hn][m][n][i2] * scale);
            rs += p;
            const int col = hn * 128 + c4 * 32 + n * 16 + lm;         // C/D: col=lm
            *(unsigned short*)(rowp + ((col * 2) ^ sw)) = f2bf(p);
        }
        rs += __shfl_xor(rs, 1);
        rs += __shfl_xor(rs, 2);
        rs += __shfl_xor(rs, 4);
        rs += __shfl_xor(rs, 8);
        if (lm == 0) atomicAdd(lr + bm + row, rs);
    }
    asm volatile("s_waitcnt lgkmcnt(0)" ::: "memory");
    __builtin_amdgcn_s_barrier();
    __builtin_amdgcn_sched_barrier(0);
    #pragma unroll
    for (int j = 0; j < 16; ++j) {                        // 256 rows x 512 B out
        const int row = j * 16 + (tid >> 5);
        const int cg  = tid & 31;
        const uint4 v = *(const uint4*)((const char*)Ct + row * 512 + ((cg * 16) ^ ((row & 7) << 4)));
        *(uint4*)(Cz + (size_t)(bm + row) * N + bn + cg * 8) = v;
    }
#undef STG
#undef STG_TILE
#undef LD_AF
#undef LD_BF
#undef MM
#undef TILE_BODY
}

// ---------- launch ----------
extern "C" void kernel_launch(void* const* d_in, const int* in_sizes, int n_in,
                              void* d_out, int out_size, void* d_ws, size_t ws_size,
                              hipStream_t stream) {
    const float* x  = (const float*)d_in[0];
    const float* rp = (const float*)d_in[1];
    const float* Wq = (const float*)d_in[2];
    const float* bq = (const float*)d_in[3];
    const float* Wk = (const float*)d_in[4];
    const float* bk = (const float*)d_in[5];
    const float* Wv = (const float*)d_in[6];
    const float* bv = (const float*)d_in[7];

    char* ws = (char*)d_ws;
    unsigned short* xb  = (unsigned short*)(ws + OFF_XB);
    unsigned short* sb  = (unsigned short*)(ws + OFF_SB);
    unsigned short* wqb = (unsigned short*)(ws + OFF_WQB);
    unsigned short* wkb = (unsigned short*)(ws + OFF_WKB);
    unsigned short* wvb = (unsigned short*)(ws + OFF_WVB);
    float*          bqk = (float*)(ws + OFF_BQK);
    unsigned short* qb  = (unsigned short*)(ws + OFF_QB);
    unsigned short* k2b = (unsigned short*)(ws + OFF_K2B);
    unsigned short* vtb = (unsigned short*)(ws + OFF_VTB);
    unsigned short* pb  = (unsigned short*)(ws + OFF_PB);
    float*          lrow = (float*)(ws + OFF_L);

    // 1. casts + x+rp fusion + bias prep + lrow zero
    prep_all<<<8448, 256, 0, stream>>>(x, rp, Wq, Wk, Wv, bq, bk,
                                       xb, sb, wqb, wkb, wvb, bqk, lrow);

    // 2+3. fused via z: z=0 -> Q = x@Wq^T + bq ; z=1 -> K2 = (x+rp)@Wk^T + 2bk
    gemm_bt<0, 1, 2><<<dim3(4, 128, 2), 256, 0, stream>>>(
        xb, wqb, qb, 16384, 512, 512,
        8388608, 262144, 8388608,
        bqk, 512, nullptr, 1.0f, nullptr, 0);
    // 4. V^T[b][d][k] = sum_h Wv[d,h] x[b,k,h] + bv[d]
    gemm_bt<0, 0, 2><<<dim3(32, 4, 4), 256, 0, stream>>>(
        wvb, xb, vtb, 512, 4096, 512,
        0, (long long)S * H, (long long)S * H,
        nullptr, 0, bv, 1.0f, nullptr, 0);
    // 5. P = exp(Q@K2^T / sqrt(512)); lrow += row sums  — 2-phase 256^2 kernel
    qk_exp_8ph<<<dim3(16, 16, 4), 512, 0, stream>>>(qb, k2b, pb, lrow);
    // 6. O = (P @ V) / l   (per-batch: M=4096, N=512, K=4096), BK=128 (4 panels)
    gemm_bt<1, 1, 4><<<dim3(4, 32, 4), 256, 0, stream>>>(
        pb, vtb, d_out, 4096, 512, 4096,
        (long long)S * S, (long long)S * H, (long long)S * H,
        nullptr, 0, nullptr, 1.0f, lrow, 4096);
}

// Round 5
// 331.847 us; speedup vs baseline: 1.0966x; 1.0966x over previous
//
#include <hip/hip_runtime.h>
#include <stdint.h>

// ---------- common helpers ----------
typedef __attribute__((ext_vector_type(8))) short bf16x8;   // 8 bf16 (4 VGPRs)
typedef __attribute__((ext_vector_type(4))) float f32x4;    // MFMA accumulator

#define AS1 __attribute__((address_space(1)))
#define AS3 __attribute__((address_space(3)))

// async global->LDS, 16B per lane; LDS dest = wave-uniform base + lane*16.
__device__ __forceinline__ void gl2lds16(const void* g, void* l) {
    __builtin_amdgcn_global_load_lds((const AS1 void*)g, (AS3 void*)l, 16, 0, 0);
}

__device__ __forceinline__ unsigned short f2bf(float f) {
    uint32_t u = __builtin_bit_cast(uint32_t, f);
    uint32_t r = (u + 0x7fffu + ((u >> 16) & 1u)) >> 16;    // RNE
    return (unsigned short)r;
}

// ---------- problem constants ----------
// B=4, S=4096, H=512
constexpr int S = 4096;
constexpr int H = 512;
constexpr size_t OFF_XB  = 0;                         // x  bf16   [4*4096*512]
constexpr size_t OFF_SB  = 16777216;                  // x+rp bf16 (contiguous after xb)
constexpr size_t OFF_WQB = 33554432;                  // Wq bf16 [512*512]
constexpr size_t OFF_WKB = 34078720;                  // Wk bf16 (contiguous after Wq)
constexpr size_t OFF_WVB = 34603008;
constexpr size_t OFF_BQK = 35127296;                  // fp32 [2][512]: row0=bq, row1=2*bk
constexpr size_t OFF_QB  = 35131392;                  // Q bf16 [4][4096][512]
constexpr size_t OFF_K2B = OFF_QB  + 16777216;        // K+Kr bf16 (contiguous after Q)
constexpr size_t OFF_VTB = OFF_K2B + 16777216;        // V^T bf16 [4][512][4096]
constexpr size_t OFF_PB  = OFF_VTB + 16777216;        // P = exp(scores) bf16 [4][4096][4096]
constexpr size_t OFF_L   = OFF_PB  + 134217728;       // row sums fp32 [4][4096]

// ---------- fused prep: casts, x+rp fusion, bias prep, lrow zero ----------
__global__ __launch_bounds__(256) void prep_all(const float* __restrict__ x,
                                                const float* __restrict__ rp,
                                                const float* __restrict__ wq,
                                                const float* __restrict__ wk,
                                                const float* __restrict__ wv,
                                                const float* __restrict__ bq,
                                                const float* __restrict__ bk,
                                                unsigned short* __restrict__ xb,
                                                unsigned short* __restrict__ sb,
                                                unsigned short* __restrict__ wqb,
                                                unsigned short* __restrict__ wkb,
                                                unsigned short* __restrict__ wvb,
                                                float* __restrict__ bqk,
                                                float* __restrict__ lrow) {
    if (blockIdx.x < 8192) {
        const int i = (blockIdx.x * 256 + threadIdx.x) * 4;
        float4 xv = *(const float4*)(x + i);
        float4 rv = *(const float4*)(rp + i);
        uint2 xo, so;
        xo.x = (uint32_t)f2bf(xv.x) | ((uint32_t)f2bf(xv.y) << 16);
        xo.y = (uint32_t)f2bf(xv.z) | ((uint32_t)f2bf(xv.w) << 16);
        so.x = (uint32_t)f2bf(xv.x + rv.x) | ((uint32_t)f2bf(xv.y + rv.y) << 16);
        so.y = (uint32_t)f2bf(xv.z + rv.z) | ((uint32_t)f2bf(xv.w + rv.w) << 16);
        *(uint2*)(xb + i) = xo;
        *(uint2*)(sb + i) = so;
    } else {
        const int t = (blockIdx.x - 8192) * 256 + threadIdx.x;   // 0..65535
        const int i = t * 4;
        float4 q = *(const float4*)(wq + i);
        float4 k = *(const float4*)(wk + i);
        float4 v = *(const float4*)(wv + i);
        uint2 o;
        o.x = (uint32_t)f2bf(q.x) | ((uint32_t)f2bf(q.y) << 16);
        o.y = (uint32_t)f2bf(q.z) | ((uint32_t)f2bf(q.w) << 16);
        *(uint2*)(wqb + i) = o;
        o.x = (uint32_t)f2bf(k.x) | ((uint32_t)f2bf(k.y) << 16);
        o.y = (uint32_t)f2bf(k.z) | ((uint32_t)f2bf(k.w) << 16);
        *(uint2*)(wkb + i) = o;
        o.x = (uint32_t)f2bf(v.x) | ((uint32_t)f2bf(v.y) << 16);
        o.y = (uint32_t)f2bf(v.z) | ((uint32_t)f2bf(v.w) << 16);
        *(uint2*)(wvb + i) = o;
        if (t < 128) {                                    // row0 = bq
            *(float4*)(bqk + t * 4) = *(const float4*)(bq + t * 4);
        } else if (t < 256) {                             // row1 = 2*bk
            const int u = t - 128;
            float4 b = *(const float4*)(bk + u * 4);
            *(float4*)(bqk + 512 + u * 4) = make_float4(2.f * b.x, 2.f * b.y, 2.f * b.z, 2.f * b.w);
        }
        if (t < 4096) {                                   // lrow[16384] = 0
            *(float4*)(lrow + t * 4) = make_float4(0.f, 0.f, 0.f, 0.f);
        }
    }
}

// ---------- generic bt-form bf16 MFMA GEMM: C[m,n] = f(sum_k A[m,k]*B[n,k]) ----------
// 128x128 tile, 4 waves (2x2 of 64x64), 16x16x32 bf16 MFMA, global_load_lds staging.
// K-step = 64*NP64 as NP64 [128 rows][64 elem] (128 B row) LDS panels per side.
// T2 bank-conflict swizzle (verified 0-conflict on HW in r2/r4's 256^2 kernel,
// same 16-row x 8-slot XOR pattern): 16B slot' = slot ^ (row&7), applied by
// pre-swizzling the GLOBAL source (LDS dest stays linear, required by
// global_load_lds) and XOR-ing the ds_read address identically. The old
// [128][32] panel (64 B rows) had 8 lanes per 4-bank group -> 8.9M conflict
// cycles per score dispatch; this layout removes them with zero change to tile
// shape, wave layout, barrier rhythm, or instruction counts.
// MODE 0: C bf16, v = acc*scale + bias_m[row] + bias_n[z*sBNz + col]; LDS-restaged
//         all-wave coalesced dwordx4 stores.
// MODE 1: C fp32, v = acc / rowdiv[z*sRz + row]  (direct stores)
// MODE 2: C bf16, v = exp(acc*scale); row sums atomicAdd'ed into rowdiv[z*sRz+row].
// SWZ 1: remap blocks so tiles sharing one A row-strip land on the same XCD.
template <int MODE, int SWZ, int NP64>
__global__ __launch_bounds__(256, 2)
void gemm_bt(const unsigned short* __restrict__ Abase,
             const unsigned short* __restrict__ Bbase,
             void* __restrict__ Cbase,
             int M, int N, int K,
             long long sAz, long long sBz, long long sCz,
             const float* __restrict__ bias_n, long long sBNz,
             const float* __restrict__ bias_m,
             float scale,
             float* __restrict__ rowdiv, long long sRz)
{
    int bx = blockIdx.x, by = blockIdx.y, bz = blockIdx.z;
    if (SWZ) {
        const int gx = gridDim.x, gy = gridDim.y;
        const int id  = bx + gx * (by + gridDim.y * bz);
        const int xcd = id & 7;
        const int k   = id >> 3;
        const int kg  = k / gx;
        bx = k - kg * gx;
        const int g = xcd + 8 * kg;
        const int gz = g / gy;
        by = g - gz * gy;
        bz = gz;
    }
    const int z = bz;
    const unsigned short* A  = Abase + (size_t)z * (size_t)sAz;
    const unsigned short* Bm = Bbase + (size_t)z * (size_t)sBz;
    const int bn = bx * 128;
    const int bm = by * 128;

    // LDS: A panels NP64 x [128][64] bf16 (16 KB) + B same; bf16 MODEs re-stage
    // the C tile as 128 x 136 bf16 = 34816 B (unioned with the staging area).
    constexpr int STAGE_BYTES = NP64 * 32768;
    constexpr int SMEM_BYTES = (MODE == 1) ? STAGE_BYTES
                             : (STAGE_BYTES > 34816 ? STAGE_BYTES : 34816);
    __shared__ __align__(16) char smem[SMEM_BYTES];
    char* As = smem;                       // NP64 x [128 rows][128 B]
    char* Bs = smem + NP64 * 16384;

    const int tid  = threadIdx.x;
    const int wave = tid >> 6;
    const int lane = tid & 63;
    const int lm   = lane & 15;
    const int quad = lane >> 4;
    const int wm   = (wave >> 1) * 64;
    const int wn   = (wave & 1) * 64;

    // staging coords: one gl2lds16 covers 8 rows x 128 B. Lane's LDS line:
    // row = chunkbase + wave*8 + (lane>>3), slot = lane&7. Pre-swizzled global
    // source slot = (lane&7) ^ (lane>>3)   (row&7 == lane>>3).
    const int sr = wave * 8 + (lane >> 3);          // row within 32-row chunk unit
    const int ss = ((lane & 7) ^ (lane >> 3)) * 8;  // source slot, in bf16 elems

    // k-loop read slot (bytes): row&7 == lm&7 for all fragment rows.
    const int sA0 = (quad ^ (lm & 7)) * 16;         // ks=0; ks=1 is sA0 ^ 64

    f32x4 acc[4][4] = {};

    for (int k0 = 0; k0 < K; k0 += 64 * NP64) {
        __syncthreads();                   // prev iter's ds_reads done before overwrite
        #pragma unroll
        for (int pp = 0; pp < NP64; pp++) {
            const unsigned short* Ap = A  + (size_t)(bm + sr) * K + k0 + pp * 64 + ss;
            const unsigned short* Bp = Bm + (size_t)(bn + sr) * K + k0 + pp * 64 + ss;
            char* Asp = As + pp * 16384 + wave * 1024;
            char* Bsp = Bs + pp * 16384 + wave * 1024;
            #pragma unroll
            for (int c = 0; c < 4; c++) {
                gl2lds16(Ap + (size_t)(c * 32) * K, Asp + c * 4096);
                gl2lds16(Bp + (size_t)(c * 32) * K, Bsp + c * 4096);
            }
        }
        __syncthreads();                   // drains vmcnt -> staged data visible

        #pragma unroll
        for (int pp = 0; pp < NP64; pp++) {
            #pragma unroll
            for (int ks = 0; ks < 2; ks++) {
                const int so = ks ? (sA0 ^ 64) : sA0;
                bf16x8 af[4], bfr[4];
                #pragma unroll
                for (int t = 0; t < 4; t++)
                    af[t]  = *(const bf16x8*)(As + pp * 16384 + (wm + t * 16 + lm) * 128 + so);
                #pragma unroll
                for (int t = 0; t < 4; t++)
                    bfr[t] = *(const bf16x8*)(Bs + pp * 16384 + (wn + t * 16 + lm) * 128 + so);
                #pragma unroll
                for (int mt = 0; mt < 4; mt++)
                    #pragma unroll
                    for (int nt = 0; nt < 4; nt++)
                        acc[mt][nt] = __builtin_amdgcn_mfma_f32_16x16x32_bf16(af[mt], bfr[nt], acc[mt][nt], 0, 0, 0);
            }
        }
    }

    // epilogue: C/D layout col = lane&15, row = quad*4 + reg  [m89/m91]
    if (MODE == 1) {
        float* C = (float*)Cbase + (size_t)z * (size_t)sCz;
        const float* rd = rowdiv + (size_t)z * (size_t)sRz;
        #pragma unroll
        for (int mt = 0; mt < 4; mt++) {
            #pragma unroll
            for (int i = 0; i < 4; i++) {
                const int row = bm + wm + mt * 16 + quad * 4 + i;
                const float inv = 1.0f / rd[row];
                const size_t rb = (size_t)row * (size_t)N;
                #pragma unroll
                for (int nt = 0; nt < 4; nt++) {
                    const int col = bn + wn + nt * 16 + lm;
                    C[rb + col] = acc[mt][nt][i] * inv;
                }
            }
        }
    } else {  // MODE 0 / 2: bf16 out, all-wave LDS re-stage -> coalesced dwordx4
        unsigned short* C = (unsigned short*)Cbase + (size_t)z * (size_t)sCz;
        const float* bn_ptr = (MODE == 0 && bias_n) ? bias_n + (size_t)z * (size_t)sBNz : nullptr;
        float* lr = (MODE == 2) ? rowdiv + (size_t)z * (size_t)sRz : nullptr;
        unsigned short* Ct = (unsigned short*)smem;   // 128 x 136 bf16 tile
        __syncthreads();                   // every wave done reading As/Bs
        #pragma unroll
        for (int mt = 0; mt < 4; mt++) {
            #pragma unroll
            for (int i = 0; i < 4; i++) {
                const int r = wm + mt * 16 + quad * 4 + i;     // tile-local row
                if (MODE == 0) {
                    const float badd = bias_m ? bias_m[bm + r] : 0.0f;
                    #pragma unroll
                    for (int nt = 0; nt < 4; nt++) {
                        const int col = bn + wn + nt * 16 + lm;
                        float v = acc[mt][nt][i] * scale + badd;
                        if (bn_ptr) v += bn_ptr[col];
                        Ct[r * 136 + wn + nt * 16 + lm] = f2bf(v);
                    }
                } else {
                    float rsum = 0.f;
                    #pragma unroll
                    for (int nt = 0; nt < 4; nt++) {
                        float p = __expf(acc[mt][nt][i] * scale);
                        rsum += p;
                        Ct[r * 136 + wn + nt * 16 + lm] = f2bf(p);
                    }
                    rsum += __shfl_xor(rsum, 1);
                    rsum += __shfl_xor(rsum, 2);
                    rsum += __shfl_xor(rsum, 4);
                    rsum += __shfl_xor(rsum, 8);
                    if (lm == 0) atomicAdd(lr + bm + r, rsum);
                }
            }
        }
        __syncthreads();                   // tile complete
        #pragma unroll
        for (int j = 0; j < 8; j++) {      // 128 rows x 256B, 16B per thread-access
            const int r   = (tid >> 4) + 16 * j;
            const int c16 = tid & 15;
            uint4 vv = *(const uint4*)(Ct + r * 136 + c16 * 8);
            *(uint4*)(C + (size_t)(bm + r) * (size_t)N + bn + c16 * 8) = vv;
        }
    }
}

// ---------- launch ----------
extern "C" void kernel_launch(void* const* d_in, const int* in_sizes, int n_in,
                              void* d_out, int out_size, void* d_ws, size_t ws_size,
                              hipStream_t stream) {
    const float* x  = (const float*)d_in[0];
    const float* rp = (const float*)d_in[1];
    const float* Wq = (const float*)d_in[2];
    const float* bq = (const float*)d_in[3];
    const float* Wk = (const float*)d_in[4];
    const float* bk = (const float*)d_in[5];
    const float* Wv = (const float*)d_in[6];
    const float* bv = (const float*)d_in[7];

    char* ws = (char*)d_ws;
    unsigned short* xb  = (unsigned short*)(ws + OFF_XB);
    unsigned short* sb  = (unsigned short*)(ws + OFF_SB);
    unsigned short* wqb = (unsigned short*)(ws + OFF_WQB);
    unsigned short* wkb = (unsigned short*)(ws + OFF_WKB);
    unsigned short* wvb = (unsigned short*)(ws + OFF_WVB);
    float*          bqk = (float*)(ws + OFF_BQK);
    unsigned short* qb  = (unsigned short*)(ws + OFF_QB);
    unsigned short* k2b = (unsigned short*)(ws + OFF_K2B);
    unsigned short* vtb = (unsigned short*)(ws + OFF_VTB);
    unsigned short* pb  = (unsigned short*)(ws + OFF_PB);
    float*          lrow = (float*)(ws + OFF_L);

    // 1. casts + x+rp fusion + bias prep + lrow zero (single dispatch)
    prep_all<<<8448, 256, 0, stream>>>(x, rp, Wq, Wk, Wv, bq, bk,
                                       xb, sb, wqb, wkb, wvb, bqk, lrow);

    // 2+3. fused via z: z=0 -> Q = x@Wq^T + bq ; z=1 -> K2 = (x+rp)@Wk^T + 2bk
    gemm_bt<0, 1, 1><<<dim3(4, 128, 2), 256, 0, stream>>>(
        xb, wqb, qb, 16384, 512, 512,
        8388608, 262144, 8388608,
        bqk, 512, nullptr, 1.0f, nullptr, 0);
    // 4. V^T[b][d][k] = sum_h Wv[d,h] x[b,k,h] + bv[d]   (per-batch: M=512, N=4096, K=512)
    gemm_bt<0, 0, 1><<<dim3(32, 4, 4), 256, 0, stream>>>(
        wvb, xb, vtb, 512, 4096, 512,
        0, (long long)S * H, (long long)S * H,
        nullptr, 0, bv, 1.0f, nullptr, 0);
    // 5. P = exp(Q@K2^T / sqrt(512)); lrow += row sums  (per-batch: M=N=4096, K=512)
    gemm_bt<2, 0, 1><<<dim3(32, 32, 4), 256, 0, stream>>>(
        qb, k2b, pb, 4096, 4096, 512,
        (long long)S * H, (long long)S * H, (long long)S * S,
        nullptr, 0, nullptr, 0.044194173824159216f,
        lrow, 4096);
    // 6. O = (P @ V) / l   (per-batch: M=4096, N=512, K=4096), K-step 128 (NP64=2)
    gemm_bt<1, 1, 2><<<dim3(4, 32, 4), 256, 0, stream>>>(
        pb, vtb, d_out, 4096, 512, 4096,
        (long long)S * S, (long long)S * H, (long long)S * H,
        nullptr, 0, nullptr, 1.0f, lrow, 4096);
}